// Round 2
// baseline (498.649 us; speedup 1.0000x reference)
//
#include <hip/hip_runtime.h>

// out[b,c,h,w] = x[b,c, 2h+o, 2w+p],  (o,p) = divmod(i, 2)
// B=8, C=3, H=W=2048, Ho=Wo=1024.
// Each thread produces one float4 of output (4 consecutive output cols):
//   - two consecutive float4 loads (32 B) from the selected input row
//   - wave-uniform component select (p uniform -> v_cndmask, no divergence)
//   - one float4 store (16 B/lane, coalescing sweet spot).

#define HO    1024
#define W_IN  2048

__global__ __launch_bounds__(256)
void CNN2__57801669869865_kernel(const float* __restrict__ x,
                                 const int* __restrict__ i_ptr,
                                 float* __restrict__ out,
                                 int total_vec4) {
    const int i = i_ptr[0];          // wave-uniform scalar load
    const int o = (i >> 1) & 1;      // row offset within 2x2 block
    const int p = i & 1;             // col offset within 2x2 block

    int idx = blockIdx.x * blockDim.x + threadIdx.x;
    if (idx >= total_vec4) return;

    const int w4  = idx & 255;       // which output float4 along the row (256/row)
    const int row = idx >> 8;        // (b*C + c)*Ho + h
    const int bc  = row >> 10;
    const int h   = row & (HO - 1);

    const float4* src = reinterpret_cast<const float4*>(
        x + ((size_t)bc * W_IN + (size_t)(2 * h + o)) * W_IN);
    float4 a = src[2 * w4];
    float4 b = src[2 * w4 + 1];

    float4 r;
    r.x = p ? a.y : a.x;
    r.y = p ? a.w : a.z;
    r.z = p ? b.y : b.x;
    r.w = p ? b.w : b.z;

    reinterpret_cast<float4*>(out)[idx] = r;
}

extern "C" void kernel_launch(void* const* d_in, const int* in_sizes, int n_in,
                              void* d_out, int out_size, void* d_ws, size_t ws_size,
                              hipStream_t stream) {
    const float* x = (const float*)d_in[0];
    const int* ip  = (const int*)d_in[1];
    float* out     = (float*)d_out;

    const int total_vec4 = 8 * 3 * HO * 256;   // 6,291,456 float4 outputs
    const int block = 256;
    const int grid = (total_vec4 + block - 1) / block;

    CNN2__57801669869865_kernel<<<grid, block, 0, stream>>>(x, ip, out, total_vec4);
}